// Round 1
// baseline (350.086 us; speedup 1.0000x reference)
//
#include <hip/hip_runtime.h>
#include <cstdint>
#include <math.h>

#define N 6144
#define FIN 128
#define FH 64
#define NHEADS 4
#define NC 16
#define CAP 256
#define ALPHA 0.2f
#define NT 16

__device__ __forceinline__ float wave_sum(float v) {
    #pragma unroll
    for (int off = 32; off >= 1; off >>= 1) v += __shfl_xor(v, off);
    return v;
}
__device__ __forceinline__ float wave_max(float v) {
    #pragma unroll
    for (int off = 32; off >= 1; off >>= 1) v = fmaxf(v, __shfl_xor(v, off));
    return v;
}

// Weff[h][k][f] = sum_r W0[h][r*128+k][f]   (x = tile(feature,(1,4)))
__global__ void k_reduce_w(const float* __restrict__ W0, float* __restrict__ weff) {
    int idx = blockIdx.x * 256 + threadIdx.x;           // h*8192 + k*64 + f
    if (idx >= NHEADS * FIN * FH) return;
    int f = idx & 63, k = (idx >> 6) & 127, h = idx >> 13;
    const float* base = W0 + (size_t)h * 512 * 64;
    float s = 0.f;
    #pragma unroll
    for (int r = 0; r < 4; r++) s += base[(size_t)(r * 128 + k) * 64 + f];
    weff[idx] = s;
}

// CSR build: one block per row, stream-compact nonzero columns (cap CAP, count full degree)
__global__ void k_csr(const float* __restrict__ adj, int* __restrict__ cols,
                      int* __restrict__ deg) {
    int i = blockIdx.x;
    int tid = threadIdx.x;
    int lane = tid & 63, wid = tid >> 6;
    __shared__ int wcnt[4];
    __shared__ int base;
    if (tid == 0) base = 0;
    __syncthreads();
    const float* row = adj + (size_t)i * N;
    int* crow = cols + (size_t)i * CAP;
    for (int c = 0; c < N; c += 256) {
        int j = c + tid;
        bool p = (row[j] != 0.0f);
        unsigned long long m = __ballot(p);
        int prefix = __popcll(m & ((1ull << lane) - 1ull));
        int wtot = __popcll(m);
        if (lane == 0) wcnt[wid] = wtot;
        __syncthreads();
        int wbase = 0;
        for (int w = 0; w < wid; w++) wbase += wcnt[w];
        int ctot = wcnt[0] + wcnt[1] + wcnt[2] + wcnt[3];   // register, captured before barrier
        int pos = base + wbase + prefix;
        if (p && pos < CAP) crow[pos] = j;
        __syncthreads();
        if (tid == 0) base += ctot;
        // next iteration's first __syncthreads makes base visible before it is read
    }
    __syncthreads();
    if (tid == 0) deg[i] = base;
}

// h_feat[h][n][f] = feature[n] . Weff[h][:,f]   (16 nodes per block)
__global__ void k_hgemm(const float* __restrict__ feat, const float* __restrict__ weff,
                        float* __restrict__ hfeat) {
    __shared__ float fl[NT * FIN];
    int tid = threadIdx.x;
    int n0 = blockIdx.x * NT;
    for (int idx = tid; idx < NT * FIN; idx += 256) fl[idx] = feat[(size_t)n0 * FIN + idx];
    __syncthreads();
    int f = tid & 63, h = tid >> 6;
    const float* wcol = weff + (size_t)h * FIN * FH + f;
    float acc[NT];
    #pragma unroll
    for (int nn = 0; nn < NT; nn++) acc[nn] = 0.f;
    for (int k = 0; k < FIN; k++) {
        float w = wcol[(size_t)k * FH];
        #pragma unroll
        for (int nn = 0; nn < NT; nn++) acc[nn] = fmaf(fl[nn * FIN + k], w, acc[nn]);
    }
    for (int nn = 0; nn < NT; nn++)
        hfeat[((size_t)h * N + (n0 + nn)) * FH + f] = acc[nn];
}

// s[h][n] = h_feat[h][n] . a1[h] ; t likewise
__global__ void k_st(const float* __restrict__ hfeat, const float* __restrict__ a1,
                     const float* __restrict__ a2, float* __restrict__ sb,
                     float* __restrict__ tb) {
    int n = blockIdx.x;
    int lane = threadIdx.x & 63, h = threadIdx.x >> 6;
    float v = hfeat[((size_t)h * N + n)*FH + lane];
    float s = wave_sum(v * a1[h * FH + lane]);
    float t = wave_sum(v * a2[h * FH + lane]);
    if (lane == 0) { sb[h * N + n] = s; tb[h * N + n] = t; }
}

// Sparse masked-softmax aggregation, hidden layer. One wave per (row, head).
// mode 0: sparse CSR; mode 1: deg==0 (mask is constant shift -> unmasked dense);
// mode 2: deg>CAP overflow (dense scan of adj row; masked entries exp-underflow to exactly 0)
__global__ void k_attn_hidden(const float* __restrict__ hfeat, const float* __restrict__ sb,
                              const float* __restrict__ tb, const int* __restrict__ cols,
                              const int* __restrict__ deg, const float* __restrict__ adj,
                              float* __restrict__ x1) {
    int i = blockIdx.x;
    int lane = threadIdx.x & 63, h = threadIdx.x >> 6;
    int d = deg[i];
    int mode = (d == 0) ? 1 : (d > CAP ? 2 : 0);
    int count = (mode == 0) ? d : N;
    const int* crow = cols + (size_t)i * CAP;
    const float* trow = tb + (size_t)h * N;
    const float* hrow = hfeat + (size_t)h * N * FH;
    float si = sb[h * N + i];
    float m = -INFINITY, l = 0.f, acc = 0.f;
    for (int base = 0; base < count; base += 64) {
        int idx = base + lane;
        int j = 0; float lr = -INFINITY;
        if (idx < count) {
            j = (mode == 0) ? crow[idx] : idx;
            bool ok = (mode != 2) || (adj[(size_t)i * N + j] != 0.f);
            if (ok) {
                float z = si + trow[j];
                lr = (z >= 0.f) ? z : ALPHA * z;
            }
        }
        float mc = wave_max(lr);
        float mn = fmaxf(m, mc);
        if (mn == -INFINITY) continue;            // wave-uniform
        float scale = (m == -INFINITY) ? 0.f : expf(m - mn);
        float w = (lr == -INFINITY) ? 0.f : expf(lr - mn);
        float lsum = wave_sum(w);
        l = l * scale + lsum;
        acc = acc * scale;
        int cn = min(64, count - base);
        for (int b = 0; b < cn; b++) {
            float wb = __shfl(w, b);
            if (wb > 0.f) {                       // uniform branch (wb broadcast)
                int jb = __shfl(j, b);
                acc = fmaf(wb, hrow[(size_t)jb * FH + lane], acc);
            }
        }
        m = mn;
    }
    float o = acc / l;
    o = (o > 0.f) ? o : expm1f(o);                // elu AFTER aggregation
    x1[(size_t)i * (NHEADS * FH) + h * FH + lane] = o;
}

// h2 = x1 @ Wout [256x16]; s2/t2. One wave per node: lane = f + 16*part.
__global__ void k_ogemm(const float* __restrict__ x1, const float* __restrict__ wout,
                        const float* __restrict__ a1o, const float* __restrict__ a2o,
                        float* __restrict__ h2, float* __restrict__ s2,
                        float* __restrict__ t2) {
    int w = threadIdx.x >> 6, lane = threadIdx.x & 63;
    int n = blockIdx.x * 4 + w;
    int f = lane & 15, part = lane >> 4;
    const float* xr = x1 + (size_t)n * 256 + part * 64;
    float dot = 0.f;
    for (int k = 0; k < 64; k++) dot = fmaf(xr[k], wout[(size_t)(part * 64 + k) * NC + f], dot);
    dot += __shfl_xor(dot, 16);
    dot += __shfl_xor(dot, 32);                   // all lanes in f-group hold h2[n][f]
    if (lane < NC) h2[(size_t)n * NC + lane] = dot;
    float sv = (lane < NC) ? dot * a1o[lane] : 0.f;
    float tv = (lane < NC) ? dot * a2o[lane] : 0.f;
    sv = wave_sum(sv); tv = wave_sum(tv);
    if (lane == 0) { s2[n] = sv; t2[n] = tv; }
}

// Output-layer attention + elu + class softmax. One wave per row.
__global__ void k_attn_out(const float* __restrict__ h2, const float* __restrict__ s2,
                           const float* __restrict__ t2, const int* __restrict__ cols,
                           const int* __restrict__ deg, const float* __restrict__ adj,
                           float* __restrict__ out) {
    int w = threadIdx.x >> 6, lane = threadIdx.x & 63;
    int i = blockIdx.x * 4 + w;
    int d = deg[i];
    int mode = (d == 0) ? 1 : (d > CAP ? 2 : 0);
    int count = (mode == 0) ? d : N;
    const int* crow = cols + (size_t)i * CAP;
    float si = s2[i];
    float m = -INFINITY, l = 0.f, acc = 0.f;
    for (int base = 0; base < count; base += 64) {
        int idx = base + lane;
        int j = 0; float lr = -INFINITY;
        if (idx < count) {
            j = (mode == 0) ? crow[idx] : idx;
            bool ok = (mode != 2) || (adj[(size_t)i * N + j] != 0.f);
            if (ok) {
                float z = si + t2[j];
                lr = (z >= 0.f) ? z : ALPHA * z;
            }
        }
        float mc = wave_max(lr);
        float mn = fmaxf(m, mc);
        if (mn == -INFINITY) continue;
        float scale = (m == -INFINITY) ? 0.f : expf(m - mn);
        float wv = (lr == -INFINITY) ? 0.f : expf(lr - mn);
        float lsum = wave_sum(wv);
        l = l * scale + lsum;
        acc = acc * scale;
        int cn = min(64, count - base);
        for (int b = 0; b < cn; b++) {
            float wb = __shfl(wv, b);
            if (wb > 0.f) {
                int jb = __shfl(j, b);
                if (lane < NC) acc = fmaf(wb, h2[(size_t)jb * NC + lane], acc);
            }
        }
        m = mn;
    }
    float o = acc / l;                            // lanes >= NC hold garbage, masked below
    o = (o > 0.f) ? o : expm1f(o);                // elu
    float mv = (lane < NC) ? o : -INFINITY;
    float mx = wave_max(mv);
    float e = (lane < NC) ? expf(o - mx) : 0.f;
    float se = wave_sum(e);
    if (lane < NC) out[(size_t)i * NC + lane] = e / se;
}

extern "C" void kernel_launch(void* const* d_in, const int* in_sizes, int n_in,
                              void* d_out, int out_size, void* d_ws, size_t ws_size,
                              hipStream_t stream) {
    const float* adj  = (const float*)d_in[0];   // [N,N]
    const float* feat = (const float*)d_in[1];   // [N,128]
    const float* W0   = (const float*)d_in[2];   // [4,512,64]
    const float* a1_0 = (const float*)d_in[3];   // [4,64]
    const float* a2_0 = (const float*)d_in[4];   // [4,64]
    const float* Wout = (const float*)d_in[5];   // [256,16]
    const float* a1o  = (const float*)d_in[6];   // [16]
    const float* a2o  = (const float*)d_in[7];   // [16]
    float* out = (float*)d_out;                  // [N,16]

    // workspace layout (~19.7 MB)
    float* weff  = (float*)d_ws;                 // 32768
    float* hfeat = weff + 32768;                 // 4*6144*64 = 1572864
    float* sb    = hfeat + 1572864;              // 24576
    float* tb    = sb + 24576;                   // 24576
    float* x1    = tb + 24576;                   // 6144*256 = 1572864
    float* h2    = x1 + 1572864;                 // 6144*16 = 98304
    float* s2    = h2 + 98304;                   // 6144
    float* t2    = s2 + 6144;                    // 6144
    int*   cols  = (int*)(t2 + 6144);            // 6144*256
    int*   deg   = cols + (size_t)N * CAP;       // 6144

    k_reduce_w<<<128, 256, 0, stream>>>(W0, weff);
    k_csr<<<N, 256, 0, stream>>>(adj, cols, deg);
    k_hgemm<<<N / NT, 256, 0, stream>>>(feat, weff, hfeat);
    k_st<<<N, 256, 0, stream>>>(hfeat, a1_0, a2_0, sb, tb);
    k_attn_hidden<<<N, 256, 0, stream>>>(hfeat, sb, tb, cols, deg, adj, x1);
    k_ogemm<<<N / 4, 256, 0, stream>>>(x1, Wout, a1o, a2o, h2, s2, t2);
    k_attn_out<<<N / 4, 256, 0, stream>>>(h2, s2, t2, cols, deg, adj, out);
}

// Round 2
// 279.248 us; speedup vs baseline: 1.2537x; 1.2537x over previous
//
#include <hip/hip_runtime.h>
#include <cstdint>
#include <math.h>

#define N 6144
#define FIN 128
#define FH 64
#define NHEADS 4
#define NC 16
#define CAP 512
#define ALPHA 0.2f
#define NT 16

__device__ __forceinline__ float wave_sum(float v) {
    #pragma unroll
    for (int off = 32; off >= 1; off >>= 1) v += __shfl_xor(v, off);
    return v;
}
__device__ __forceinline__ float wave_max(float v) {
    #pragma unroll
    for (int off = 32; off >= 1; off >>= 1) v = fmaxf(v, __shfl_xor(v, off));
    return v;
}

// Weff[h][k][f] = sum_r W0[h][r*128+k][f]   (x = tile(feature,(1,4)))
__global__ void k_reduce_w(const float* __restrict__ W0, float* __restrict__ weff) {
    int idx = blockIdx.x * 256 + threadIdx.x;           // h*8192 + k*64 + f
    if (idx >= NHEADS * FIN * FH) return;
    int f = idx & 63, k = (idx >> 6) & 127, h = idx >> 13;
    const float* base = W0 + (size_t)h * 512 * 64;
    float s = 0.f;
    #pragma unroll
    for (int r = 0; r < 4; r++) s += base[(size_t)(r * 128 + k) * 64 + f];
    weff[idx] = s;
}

// h_feat[h][n][f] = feature[n] . Weff[h][:,f]; fused s/t = h.a1, h.a2
__global__ void k_hgemm(const float* __restrict__ feat, const float* __restrict__ weff,
                        const float* __restrict__ a1, const float* __restrict__ a2,
                        float* __restrict__ hfeat, float* __restrict__ sb,
                        float* __restrict__ tb) {
    __shared__ float fl[NT * FIN];
    int tid = threadIdx.x;
    int n0 = blockIdx.x * NT;
    for (int idx = tid; idx < NT * FIN; idx += 256) fl[idx] = feat[(size_t)n0 * FIN + idx];
    __syncthreads();
    int f = tid & 63, h = tid >> 6;                 // one wave per head
    const float* wcol = weff + (size_t)h * FIN * FH + f;
    float acc[NT];
    #pragma unroll
    for (int nn = 0; nn < NT; nn++) acc[nn] = 0.f;
    for (int k = 0; k < FIN; k++) {
        float w = wcol[(size_t)k * FH];
        #pragma unroll
        for (int nn = 0; nn < NT; nn++) acc[nn] = fmaf(fl[nn * FIN + k], w, acc[nn]);
    }
    float a1v = a1[h * FH + f], a2v = a2[h * FH + f];
    #pragma unroll
    for (int nn = 0; nn < NT; nn++) {
        hfeat[((size_t)h * N + (n0 + nn)) * FH + f] = acc[nn];
        float s = wave_sum(acc[nn] * a1v);
        float t = wave_sum(acc[nn] * a2v);
        if ((tid & 63) == 0) {
            sb[h * N + n0 + nn] = s;
            tb[h * N + n0 + nn] = t;
        }
    }
}

// Fused: CSR build (LDS compaction) + hidden-layer masked softmax aggregation.
// One block per row; wave = head. Writes cols/deg for the output layer.
__global__ void k_row(const float* __restrict__ adj, const float* __restrict__ hfeat,
                      const float* __restrict__ sb, const float* __restrict__ tb,
                      int* __restrict__ cols, int* __restrict__ deg,
                      float* __restrict__ x1) {
    int i = blockIdx.x;
    int tid = threadIdx.x;
    int lane = tid & 63, h = tid >> 6;
    __shared__ int lidx[CAP];
    __shared__ int cnt;
    if (tid == 0) cnt = 0;
    __syncthreads();

    // ---- scan: float4 per lane, wave-ballot compaction, no block barriers ----
    const float4* rowv = (const float4*)(adj + (size_t)i * N);
    unsigned long long lmask = (1ull << lane) - 1ull;
    #pragma unroll
    for (int it = 0; it < N / 1024; it++) {
        int v = it * 256 + tid;
        float4 rv = rowv[v];
        int jb = 4 * v;
        bool p[4] = {rv.x != 0.f, rv.y != 0.f, rv.z != 0.f, rv.w != 0.f};
        #pragma unroll
        for (int c = 0; c < 4; c++) {
            unsigned long long m = __ballot(p[c]);
            int tot = __popcll(m);
            if (tot) {                                   // wave-uniform
                int prefix = __popcll(m & lmask);
                int wb;
                if (lane == 0) wb = atomicAdd(&cnt, tot);
                wb = __shfl(wb, 0);
                int pos = wb + prefix;
                if (p[c] && pos < CAP) lidx[pos] = jb + c;
            }
        }
    }
    __syncthreads();
    int d = cnt;
    if (tid == 0) deg[i] = d;
    for (int t = tid; t < min(d, CAP); t += 256) cols[(size_t)i * CAP + t] = lidx[t];

    // ---- per-head online-softmax aggregation ----
    int mode = (d == 0) ? 1 : (d > CAP ? 2 : 0);
    int count = (mode == 0) ? d : N;
    const float* trow = tb + (size_t)h * N;
    const float* hrow = hfeat + (size_t)h * N * FH;
    float si = sb[h * N + i];
    int q = lane >> 4, fo = (lane & 15) * 4;             // quarter-wave: 4 neighbors x float4
    float m = -INFINITY, l = 0.f;
    float4 acc = {0.f, 0.f, 0.f, 0.f};
    for (int base = 0; base < count; base += 64) {
        int idx = base + lane;
        int j = 0; float lr = -INFINITY;
        if (idx < count) {
            j = (mode == 0) ? lidx[idx] : idx;
            bool ok = (mode != 2) || (adj[(size_t)i * N + j] != 0.f);
            if (ok) {
                float z = si + trow[j];
                lr = (z >= 0.f) ? z : ALPHA * z;
            }
        }
        float mc = wave_max(lr);
        float mn = fmaxf(m, mc);
        if (mn == -INFINITY) continue;                   // wave-uniform
        float scale = (m == -INFINITY) ? 0.f : expf(m - mn);
        float w = (lr == -INFINITY) ? 0.f : expf(lr - mn);
        l = l * scale + wave_sum(w);
        acc.x *= scale; acc.y *= scale; acc.z *= scale; acc.w *= scale;
        int cn = min(64, count - base);
        #pragma unroll 4
        for (int b = 0; b < cn; b += 4) {                // 4 neighbors / iter, 16B loads
            float wb = __shfl(w, b + q);
            int jn = __shfl(j, b + q);
            float4 hv = *(const float4*)(hrow + (size_t)jn * FH + fo);
            acc.x = fmaf(wb, hv.x, acc.x);
            acc.y = fmaf(wb, hv.y, acc.y);
            acc.z = fmaf(wb, hv.z, acc.z);
            acc.w = fmaf(wb, hv.w, acc.w);
        }
        m = mn;
    }
    // reduce the 4 quarters
    #pragma unroll
    for (int off = 16; off <= 32; off <<= 1) {
        acc.x += __shfl_xor(acc.x, off);
        acc.y += __shfl_xor(acc.y, off);
        acc.z += __shfl_xor(acc.z, off);
        acc.w += __shfl_xor(acc.w, off);
    }
    if (lane < 16) {
        float linv = 1.f / l;
        float4 o;
        o.x = acc.x * linv; o.y = acc.y * linv; o.z = acc.z * linv; o.w = acc.w * linv;
        o.x = (o.x > 0.f) ? o.x : expm1f(o.x);
        o.y = (o.y > 0.f) ? o.y : expm1f(o.y);
        o.z = (o.z > 0.f) ? o.z : expm1f(o.z);
        o.w = (o.w > 0.f) ? o.w : expm1f(o.w);
        *(float4*)(x1 + (size_t)i * (NHEADS * FH) + h * FH + fo) = o;
    }
}

// h2 = x1 @ Wout [256x16]; s2/t2. One wave per node: lane = f + 16*part.
__global__ void k_ogemm(const float* __restrict__ x1, const float* __restrict__ wout,
                        const float* __restrict__ a1o, const float* __restrict__ a2o,
                        float* __restrict__ h2, float* __restrict__ s2,
                        float* __restrict__ t2) {
    int w = threadIdx.x >> 6, lane = threadIdx.x & 63;
    int n = blockIdx.x * 4 + w;
    int f = lane & 15, part = lane >> 4;
    const float* xr = x1 + (size_t)n * 256 + part * 64;
    float dot = 0.f;
    for (int k = 0; k < 64; k++) dot = fmaf(xr[k], wout[(size_t)(part * 64 + k) * NC + f], dot);
    dot += __shfl_xor(dot, 16);
    dot += __shfl_xor(dot, 32);
    if (lane < NC) h2[(size_t)n * NC + lane] = dot;
    float sv = (lane < NC) ? dot * a1o[lane] : 0.f;
    float tv = (lane < NC) ? dot * a2o[lane] : 0.f;
    sv = wave_sum(sv); tv = wave_sum(tv);
    if (lane == 0) { s2[n] = sv; t2[n] = tv; }
}

// Output-layer attention + elu + class softmax. One wave per row, quarter-wave gather.
__global__ void k_attn_out(const float* __restrict__ h2, const float* __restrict__ s2,
                           const float* __restrict__ t2, const int* __restrict__ cols,
                           const int* __restrict__ deg, const float* __restrict__ adj,
                           float* __restrict__ out) {
    int w = threadIdx.x >> 6, lane = threadIdx.x & 63;
    int i = blockIdx.x * 4 + w;
    int d = deg[i];
    int mode = (d == 0) ? 1 : (d > CAP ? 2 : 0);
    int count = (mode == 0) ? d : N;
    const int* crow = cols + (size_t)i * CAP;
    float si = s2[i];
    int f = lane & 15, q = lane >> 4;
    float m = -INFINITY, l = 0.f, acc = 0.f;
    for (int base = 0; base < count; base += 64) {
        int idx = base + lane;
        int j = 0; float lr = -INFINITY;
        if (idx < count) {
            j = (mode == 0) ? crow[idx] : idx;
            bool ok = (mode != 2) || (adj[(size_t)i * N + j] != 0.f);
            if (ok) {
                float z = si + t2[j];
                lr = (z >= 0.f) ? z : ALPHA * z;
            }
        }
        float mc = wave_max(lr);
        float mn = fmaxf(m, mc);
        if (mn == -INFINITY) continue;
        float scale = (m == -INFINITY) ? 0.f : expf(m - mn);
        float wv = (lr == -INFINITY) ? 0.f : expf(lr - mn);
        l = l * scale + wave_sum(wv);
        acc *= scale;
        int cn = min(64, count - base);
        #pragma unroll 4
        for (int b = 0; b < cn; b += 4) {                // 4 neighbors / iter
            float wb = __shfl(wv, b + q);
            int jn = __shfl(j, b + q);
            acc = fmaf(wb, h2[(size_t)jn * NC + f], acc);
        }
        m = mn;
    }
    acc += __shfl_xor(acc, 16);
    acc += __shfl_xor(acc, 32);                          // sum quarters
    float o = acc / l;
    o = (o > 0.f) ? o : expm1f(o);                       // elu
    float mv = (lane < NC) ? o : -INFINITY;
    float mx = wave_max(mv);
    float e = (lane < NC) ? expf(o - mx) : 0.f;
    float se = wave_sum(e);
    if (lane < NC) out[(size_t)i * NC + lane] = e / se;
}

extern "C" void kernel_launch(void* const* d_in, const int* in_sizes, int n_in,
                              void* d_out, int out_size, void* d_ws, size_t ws_size,
                              hipStream_t stream) {
    const float* adj  = (const float*)d_in[0];   // [N,N]
    const float* feat = (const float*)d_in[1];   // [N,128]
    const float* W0   = (const float*)d_in[2];   // [4,512,64]
    const float* a1_0 = (const float*)d_in[3];   // [4,64]
    const float* a2_0 = (const float*)d_in[4];   // [4,64]
    const float* Wout = (const float*)d_in[5];   // [256,16]
    const float* a1o  = (const float*)d_in[6];   // [16]
    const float* a2o  = (const float*)d_in[7];   // [16]
    float* out = (float*)d_out;                  // [N,16]

    float* weff  = (float*)d_ws;                 // 32768
    float* hfeat = weff + 32768;                 // 4*6144*64 = 1572864
    float* sb    = hfeat + 1572864;              // 24576
    float* tb    = sb + 24576;                   // 24576
    float* x1    = tb + 24576;                   // 6144*256 = 1572864
    float* h2    = x1 + 1572864;                 // 6144*16 = 98304
    float* s2    = h2 + 98304;                   // 6144
    float* t2    = s2 + 6144;                    // 6144
    int*   cols  = (int*)(t2 + 6144);            // 6144*512
    int*   deg   = cols + (size_t)N * CAP;       // 6144

    k_reduce_w<<<128, 256, 0, stream>>>(W0, weff);
    k_hgemm<<<N / NT, 256, 0, stream>>>(feat, weff, a1_0, a2_0, hfeat, sb, tb);
    k_row<<<N, 256, 0, stream>>>(adj, hfeat, sb, tb, cols, deg, x1);
    k_ogemm<<<N / 4, 256, 0, stream>>>(x1, Wout, a1o, a2o, h2, s2, t2);
    k_attn_out<<<N / 4, 256, 0, stream>>>(h2, s2, t2, cols, deg, adj, out);
}

// Round 3
// 261.610 us; speedup vs baseline: 1.3382x; 1.0674x over previous
//
#include <hip/hip_runtime.h>
#include <cstdint>
#include <math.h>

#define N 6144
#define FIN 128
#define FH 64
#define NHEADS 4
#define NC 16
#define CAP 512
#define ALPHA 0.2f
#define NT 16

__device__ __forceinline__ float wave_sum(float v) {
    #pragma unroll
    for (int off = 32; off >= 1; off >>= 1) v += __shfl_xor(v, off);
    return v;
}
__device__ __forceinline__ float wave_max(float v) {
    #pragma unroll
    for (int off = 32; off >= 1; off >>= 1) v = fmaxf(v, __shfl_xor(v, off));
    return v;
}

// Weff[h][k][f] = sum_r W0[h][r*128+k][f]   (x = tile(feature,(1,4)))
__global__ void k_reduce_w(const float* __restrict__ W0, float* __restrict__ weff) {
    int idx = blockIdx.x * 256 + threadIdx.x;           // h*8192 + k*64 + f
    if (idx >= NHEADS * FIN * FH) return;
    int f = idx & 63, k = (idx >> 6) & 127, h = idx >> 13;
    const float* base = W0 + (size_t)h * 512 * 64;
    float s = 0.f;
    #pragma unroll
    for (int r = 0; r < 4; r++) s += base[(size_t)(r * 128 + k) * 64 + f];
    weff[idx] = s;
}

// h_feat[h][n][f] = feature[n] . Weff[h][:,f]; fused s/t = h.a1, h.a2
__global__ void k_hgemm(const float* __restrict__ feat, const float* __restrict__ weff,
                        const float* __restrict__ a1, const float* __restrict__ a2,
                        float* __restrict__ hfeat, float* __restrict__ sb,
                        float* __restrict__ tb) {
    __shared__ float fl[NT * FIN];
    int tid = threadIdx.x;
    int n0 = blockIdx.x * NT;
    for (int idx = tid; idx < NT * FIN; idx += 256) fl[idx] = feat[(size_t)n0 * FIN + idx];
    __syncthreads();
    int f = tid & 63, h = tid >> 6;                 // one wave per head
    const float* wcol = weff + (size_t)h * FIN * FH + f;
    float acc[NT];
    #pragma unroll
    for (int nn = 0; nn < NT; nn++) acc[nn] = 0.f;
    for (int k = 0; k < FIN; k++) {
        float w = wcol[(size_t)k * FH];
        #pragma unroll
        for (int nn = 0; nn < NT; nn++) acc[nn] = fmaf(fl[nn * FIN + k], w, acc[nn]);
    }
    float a1v = a1[h * FH + f], a2v = a2[h * FH + f];
    #pragma unroll
    for (int nn = 0; nn < NT; nn++) {
        hfeat[((size_t)h * N + (n0 + nn)) * FH + f] = acc[nn];
        float s = wave_sum(acc[nn] * a1v);
        float t = wave_sum(acc[nn] * a2v);
        if ((tid & 63) == 0) {
            sb[h * N + n0 + nn] = s;
            tb[h * N + n0 + nn] = t;
        }
    }
}

// Fused per-row megakernel: adj scan (hoisted loads, wave-ballot compaction into LDS)
// + hidden-layer online-softmax aggregation (wave = head) + elu
// + output-layer GEMM (x1_row @ Wout) + s2/t2.  Writes cols/deg for k_attn_out.
__global__ void k_row(const float* __restrict__ adj, const float* __restrict__ hfeat,
                      const float* __restrict__ sb, const float* __restrict__ tb,
                      const float* __restrict__ wout, const float* __restrict__ a1o,
                      const float* __restrict__ a2o,
                      int* __restrict__ cols, int* __restrict__ deg,
                      float* __restrict__ h2, float* __restrict__ s2,
                      float* __restrict__ t2) {
    int i = blockIdx.x;
    int tid = threadIdx.x;
    int lane = tid & 63, h = tid >> 6;
    __shared__ int lidx[CAP];
    __shared__ float xrow[NHEADS * FH];
    __shared__ int cnt;
    if (tid == 0) cnt = 0;
    __syncthreads();

    // ---- scan: ALL 6 float4 loads hoisted (independent, in flight together) ----
    const float4* rowv = (const float4*)(adj + (size_t)i * N);
    float4 rv[6];
    #pragma unroll
    for (int it = 0; it < 6; it++) rv[it] = rowv[it * 256 + tid];
    unsigned long long lmask = (1ull << lane) - 1ull;
    #pragma unroll
    for (int it = 0; it < 6; it++) {
        int jb = (it * 256 + tid) * 4;
        bool p[4] = {rv[it].x != 0.f, rv[it].y != 0.f, rv[it].z != 0.f, rv[it].w != 0.f};
        #pragma unroll
        for (int c = 0; c < 4; c++) {
            unsigned long long mm = __ballot(p[c]);
            int tot = __popcll(mm);
            if (tot) {                                   // wave-uniform
                int prefix = __popcll(mm & lmask);
                int wb;
                if (lane == 0) wb = atomicAdd(&cnt, tot);
                wb = __shfl(wb, 0);
                int pos = wb + prefix;
                if (p[c] && pos < CAP) lidx[pos] = jb + c;
            }
        }
    }
    __syncthreads();
    int d = cnt;
    if (tid == 0) deg[i] = d;
    for (int t = tid; t < min(d, CAP); t += 256) cols[(size_t)i * CAP + t] = lidx[t];

    // ---- per-head online-softmax aggregation (quarter-wave: 4 neighbors x float4) ----
    int mode = (d == 0) ? 1 : (d > CAP ? 2 : 0);
    int count = (mode == 0) ? d : N;
    const float* trow = tb + (size_t)h * N;
    const float* hrow = hfeat + (size_t)h * N * FH;
    float si = sb[h * N + i];
    int q = lane >> 4, fo = (lane & 15) * 4;
    float m = -INFINITY, l = 0.f;
    float4 acc = {0.f, 0.f, 0.f, 0.f};
    for (int base = 0; base < count; base += 64) {
        int idx = base + lane;
        int j = 0; float lr = -INFINITY;
        if (idx < count) {
            j = (mode == 0) ? lidx[idx] : idx;
            bool ok = (mode != 2) || (adj[(size_t)i * N + j] != 0.f);
            if (ok) {
                float z = si + trow[j];
                lr = (z >= 0.f) ? z : ALPHA * z;
            }
        }
        float mc = wave_max(lr);
        float mn = fmaxf(m, mc);
        if (mn == -INFINITY) continue;                   // wave-uniform
        float scale = (m == -INFINITY) ? 0.f : expf(m - mn);
        float w = (lr == -INFINITY) ? 0.f : expf(lr - mn);
        l = l * scale + wave_sum(w);
        acc.x *= scale; acc.y *= scale; acc.z *= scale; acc.w *= scale;
        int cn = min(64, count - base);
        #pragma unroll 4
        for (int b = 0; b < cn; b += 4) {
            float wb = __shfl(w, b + q);
            int jn = __shfl(j, b + q);
            float4 hv = *(const float4*)(hrow + (size_t)jn * FH + fo);
            acc.x = fmaf(wb, hv.x, acc.x);
            acc.y = fmaf(wb, hv.y, acc.y);
            acc.z = fmaf(wb, hv.z, acc.z);
            acc.w = fmaf(wb, hv.w, acc.w);
        }
        m = mn;
    }
    #pragma unroll
    for (int off = 16; off <= 32; off <<= 1) {
        acc.x += __shfl_xor(acc.x, off);
        acc.y += __shfl_xor(acc.y, off);
        acc.z += __shfl_xor(acc.z, off);
        acc.w += __shfl_xor(acc.w, off);
    }
    if (lane < 16) {
        float linv = 1.f / l;
        float4 o;
        o.x = acc.x * linv; o.y = acc.y * linv; o.z = acc.z * linv; o.w = acc.w * linv;
        o.x = (o.x > 0.f) ? o.x : expm1f(o.x);
        o.y = (o.y > 0.f) ? o.y : expm1f(o.y);
        o.z = (o.z > 0.f) ? o.z : expm1f(o.z);
        o.w = (o.w > 0.f) ? o.w : expm1f(o.w);
        *(float4*)(xrow + h * FH + fo) = o;              // x1 row stays in LDS
    }
    __syncthreads();

    // ---- fused output GEMM: h2[i] = xrow @ Wout; s2/t2 (wave 0 only) ----
    if (h == 0) {
        int f = lane & 15, part = lane >> 4;
        float dot = 0.f;
        #pragma unroll
        for (int k = 0; k < 64; k++)
            dot = fmaf(xrow[part * 64 + k], wout[(size_t)(part * 64 + k) * NC + f], dot);
        dot += __shfl_xor(dot, 16);
        dot += __shfl_xor(dot, 32);
        if (lane < NC) h2[(size_t)i * NC + lane] = dot;
        float sv = (lane < NC) ? dot * a1o[lane] : 0.f;
        float tv = (lane < NC) ? dot * a2o[lane] : 0.f;
        sv = wave_sum(sv); tv = wave_sum(tv);
        if (lane == 0) { s2[i] = sv; t2[i] = tv; }
    }
}

// Output-layer attention + elu + class softmax. One wave per row, quarter-wave gather.
__global__ void k_attn_out(const float* __restrict__ h2, const float* __restrict__ s2,
                           const float* __restrict__ t2, const int* __restrict__ cols,
                           const int* __restrict__ deg, const float* __restrict__ adj,
                           float* __restrict__ out) {
    int w = threadIdx.x >> 6, lane = threadIdx.x & 63;
    int i = blockIdx.x * 4 + w;
    int d = deg[i];
    int mode = (d == 0) ? 1 : (d > CAP ? 2 : 0);
    int count = (mode == 0) ? d : N;
    const int* crow = cols + (size_t)i * CAP;
    float si = s2[i];
    int f = lane & 15, q = lane >> 4;
    float m = -INFINITY, l = 0.f, acc = 0.f;
    for (int base = 0; base < count; base += 64) {
        int idx = base + lane;
        int j = 0; float lr = -INFINITY;
        if (idx < count) {
            j = (mode == 0) ? crow[idx] : idx;
            bool ok = (mode != 2) || (adj[(size_t)i * N + j] != 0.f);
            if (ok) {
                float z = si + t2[j];
                lr = (z >= 0.f) ? z : ALPHA * z;
            }
        }
        float mc = wave_max(lr);
        float mn = fmaxf(m, mc);
        if (mn == -INFINITY) continue;
        float scale = (m == -INFINITY) ? 0.f : expf(m - mn);
        float wv = (lr == -INFINITY) ? 0.f : expf(lr - mn);
        l = l * scale + wave_sum(wv);
        acc *= scale;
        int cn = min(64, count - base);
        #pragma unroll 4
        for (int b = 0; b < cn; b += 4) {
            float wb = __shfl(wv, b + q);
            int jn = __shfl(j, b + q);
            acc = fmaf(wb, h2[(size_t)jn * NC + f], acc);
        }
        m = mn;
    }
    acc += __shfl_xor(acc, 16);
    acc += __shfl_xor(acc, 32);
    float o = acc / l;
    o = (o > 0.f) ? o : expm1f(o);                       // elu
    float mv = (lane < NC) ? o : -INFINITY;
    float mx = wave_max(mv);
    float e = (lane < NC) ? expf(o - mx) : 0.f;
    float se = wave_sum(e);
    if (lane < NC) out[(size_t)i * NC + lane] = e / se;
}

extern "C" void kernel_launch(void* const* d_in, const int* in_sizes, int n_in,
                              void* d_out, int out_size, void* d_ws, size_t ws_size,
                              hipStream_t stream) {
    const float* adj  = (const float*)d_in[0];   // [N,N]
    const float* feat = (const float*)d_in[1];   // [N,128]
    const float* W0   = (const float*)d_in[2];   // [4,512,64]
    const float* a1_0 = (const float*)d_in[3];   // [4,64]
    const float* a2_0 = (const float*)d_in[4];   // [4,64]
    const float* Wout = (const float*)d_in[5];   // [256,16]
    const float* a1o  = (const float*)d_in[6];   // [16]
    const float* a2o  = (const float*)d_in[7];   // [16]
    float* out = (float*)d_out;                  // [N,16]

    float* weff  = (float*)d_ws;                 // 32768
    float* hfeat = weff + 32768;                 // 4*6144*64 = 1572864
    float* sb    = hfeat + 1572864;              // 24576
    float* tb    = sb + 24576;                   // 24576
    float* h2    = tb + 24576;                   // 6144*16 = 98304
    float* s2    = h2 + 98304;                   // 6144
    float* t2    = s2 + 6144;                    // 6144
    int*   cols  = (int*)(t2 + 6144);            // 6144*512
    int*   deg   = cols + (size_t)N * CAP;       // 6144

    k_reduce_w<<<128, 256, 0, stream>>>(W0, weff);
    k_hgemm<<<N / NT, 256, 0, stream>>>(feat, weff, a1_0, a2_0, hfeat, sb, tb);
    k_row<<<N, 256, 0, stream>>>(adj, hfeat, sb, tb, Wout, a1o, a2o,
                                 cols, deg, h2, s2, t2);
    k_attn_out<<<N / 4, 256, 0, stream>>>(h2, s2, t2, cols, deg, adj, out);
}